// Round 9
// baseline (695.728 us; speedup 1.0000x reference)
//
#include <hip/hip_runtime.h>
#include <hip/hip_bf16.h>

#define N_NODES 100000
#define N_EDGES 3200000
#define F_IN    128
#define H1F     64
#define H2F     32
#define NCLS    32
#define SCAN_BLOCK 1024
#define SCAN_CHUNKS ((N_NODES + SCAN_BLOCK - 1) / SCAN_BLOCK)   // 98
#define NTILES (N_NODES / 16)                                   // 6250 exact

typedef __attribute__((ext_vector_type(8))) short bf16x8;
typedef __attribute__((ext_vector_type(4))) float f32x4;

static __device__ __forceinline__ float b2f(__hip_bfloat16 v) {
    return __bfloat162float(v);
}
static __device__ __forceinline__ float us2f(unsigned short u) {
    return __uint_as_float(((unsigned)u) << 16);
}
static __device__ __forceinline__ unsigned short f2us(float f) {
    __hip_bfloat16 h = __float2bfloat16(f);
    return *(unsigned short*)&h;
}
static __device__ __forceinline__ float ld(const void* p, size_t i, int isbf) {
    return isbf ? b2f(((const __hip_bfloat16*)p)[i]) : ((const float*)p)[i];
}

// flags[0] = edge_index is int64 ; flags[1] = float tensors are bf16

__global__ void k_detect(const void* xbuf, const void* eibuf, int* flags) {
    if (threadIdx.x != 0 || blockIdx.x != 0) return;
    const unsigned* ew = (const unsigned*)eibuf;
    int z = 0;
    for (int k = 0; k < 256; ++k) z += (ew[2 * k + 1] == 0u) ? 1 : 0;
    flags[0] = (z >= 200) ? 1 : 0;
    const unsigned* xw = (const unsigned*)xbuf;
    int inr = 0;
    for (int k = 0; k < 256; ++k) {
        unsigned fb = (xw[k] & 0xFFFFu) << 16;
        float a = fabsf(__uint_as_float(fb));
        inr += (a >= 1e-4f && a <= 20.0f) ? 1 : 0;
    }
    flags[1] = (inr >= 160) ? 1 : 0;
}

// histogram + per-edge rank (aux) in ONE pass; 4 edges/thread, int4 loads
__global__ void k_count(const int* __restrict__ ei, int* __restrict__ deg,
                        int* __restrict__ aux, const int* __restrict__ flags) {
    int t = blockIdx.x * blockDim.x + threadIdx.x;
    int e0 = t * 4;
    if (e0 >= N_EDGES) return;
    int d[4];
    if (flags[0]) {
        const int4* p = (const int4*)(ei + 2 * (size_t)(N_EDGES + e0));
        int4 a = p[0], b = p[1];
        d[0] = a.x; d[1] = a.z; d[2] = b.x; d[3] = b.z;
    } else {
        int4 a = *(const int4*)(ei + (size_t)N_EDGES + e0);
        d[0] = a.x; d[1] = a.y; d[2] = a.z; d[3] = a.w;
    }
    int p0 = ((unsigned)d[0] < N_NODES) ? atomicAdd(&deg[d[0]], 1) : 0;
    int p1 = ((unsigned)d[1] < N_NODES) ? atomicAdd(&deg[d[1]], 1) : 0;
    int p2 = ((unsigned)d[2] < N_NODES) ? atomicAdd(&deg[d[2]], 1) : 0;
    int p3 = ((unsigned)d[3] < N_NODES) ? atomicAdd(&deg[d[3]], 1) : 0;
    *(int4*)(aux + e0) = make_int4(p0, p1, p2, p3);
}

__global__ void k_dinv(const int* __restrict__ deg, float* __restrict__ dinv) {
    int i = blockIdx.x * blockDim.x + threadIdx.x;
    if (i < N_NODES) dinv[i] = rsqrtf((float)deg[i] + 1.0f);  // +1 self-loop
}

// ---------- 3-phase exclusive scan of deg -> rowptr ----------
__global__ void k_scanA(const int* __restrict__ deg, int* __restrict__ partial) {
    __shared__ int red[16];
    int b = blockIdx.x, t = threadIdx.x;
    int i = b * SCAN_BLOCK + t;
    int v = (i < N_NODES) ? deg[i] : 0;
    for (int off = 32; off; off >>= 1) v += __shfl_down(v, off, 64);
    if ((t & 63) == 0) red[t >> 6] = v;
    __syncthreads();
    if (t == 0) {
        int s = 0;
        for (int k = 0; k < 16; ++k) s += red[k];
        partial[b] = s;
    }
}

__global__ void k_scanB(const int* __restrict__ partial, int* __restrict__ chunkoff) {
    if (threadIdx.x != 0 || blockIdx.x != 0) return;
    int run = 0;
    for (int b = 0; b < SCAN_CHUNKS; ++b) { chunkoff[b] = run; run += partial[b]; }
}

__global__ void k_scanC(const int* __restrict__ deg, const int* __restrict__ chunkoff,
                        int* __restrict__ rowptr) {
    __shared__ int wsum[16];
    int b = blockIdx.x, t = threadIdx.x, lane = t & 63, w = t >> 6;
    int i = b * SCAN_BLOCK + t;
    int v = (i < N_NODES) ? deg[i] : 0;
    for (int off = 1; off < 64; off <<= 1) {
        int u = __shfl_up(v, off, 64);
        if (lane >= off) v += u;
    }
    if (lane == 63) wsum[w] = v;
    __syncthreads();
    if (t == 0) {
        int run = 0;
        for (int k = 0; k < 16; ++k) { int s = wsum[k]; wsum[k] = run; run += s; }
    }
    __syncthreads();
    int incl = v + wsum[w] + chunkoff[b];
    if (i < N_NODES) rowptr[i + 1] = incl;
    if (b == 0 && t == 0) rowptr[0] = 0;
}

// atomic-free CSR fill using precomputed ranks
__global__ void k_scatter(const int* __restrict__ ei, const int* __restrict__ aux,
                          const int* __restrict__ rowptr, int* __restrict__ csr,
                          const int* __restrict__ flags) {
    int t = blockIdx.x * blockDim.x + threadIdx.x;
    int e0 = t * 4;
    if (e0 >= N_EDGES) return;
    int s[4], d[4];
    if (flags[0]) {
        const int4* ps = (const int4*)(ei + 2 * (size_t)e0);
        int4 a = ps[0], b = ps[1];
        s[0] = a.x; s[1] = a.z; s[2] = b.x; s[3] = b.z;
        const int4* pd = (const int4*)(ei + 2 * (size_t)(N_EDGES + e0));
        int4 c = pd[0], g = pd[1];
        d[0] = c.x; d[1] = c.z; d[2] = g.x; d[3] = g.z;
    } else {
        int4 a = *(const int4*)(ei + (size_t)e0);
        s[0] = a.x; s[1] = a.y; s[2] = a.z; s[3] = a.w;
        int4 c = *(const int4*)(ei + (size_t)N_EDGES + e0);
        d[0] = c.x; d[1] = c.y; d[2] = c.z; d[3] = c.w;
    }
    int4 av = *(const int4*)(aux + e0);
    int a4[4] = { av.x, av.y, av.z, av.w };
#pragma unroll
    for (int j = 0; j < 4; ++j) {
        if ((unsigned)s[j] < N_NODES && (unsigned)d[j] < N_NODES)
            csr[rowptr[d[j]] + a4[j]] = s[j];
    }
}

// ---------------- GEMM1 via MFMA: h1(bf16) = x @ W1 ; wave per 16-node tile ----------------
// A-frag: A[m=lane&15][k=quad*8+j]  B-frag: B[k=quad*8+j][n=lane&15]
// C/D:    col=lane&15, row=quad*4+reg   (m89-verified)
__global__ void k_gemm1(const void* __restrict__ x, const void* __restrict__ W1,
                        unsigned short* __restrict__ h1, const int* __restrict__ flags) {
    int tile = (blockIdx.x * blockDim.x + threadIdx.x) >> 6;
    int lane = threadIdx.x & 63;
    if (tile >= NTILES) return;
    int col = lane & 15, quad = lane >> 4;

    if (flags[1]) {
        const short* xp = (const short*)x;
        const short* wp = (const short*)W1;
        // B fragments of W1: [K-chunk][feat-group]
        bf16x8 bfr[4][4];
#pragma unroll
        for (int kc = 0; kc < 4; ++kc)
#pragma unroll
            for (int fg = 0; fg < 4; ++fg)
#pragma unroll
                for (int j = 0; j < 8; ++j)
                    bfr[kc][fg][j] = wp[(kc * 32 + quad * 8 + j) * H1F + fg * 16 + col];
        // A fragments of x (16B contiguous per lane per K-chunk)
        bf16x8 afr[4];
#pragma unroll
        for (int kc = 0; kc < 4; ++kc)
            afr[kc] = *(const bf16x8*)(xp + (size_t)(tile * 16 + col) * F_IN + kc * 32 + quad * 8);
        f32x4 acc[4];
#pragma unroll
        for (int fg = 0; fg < 4; ++fg)
#pragma unroll
            for (int r = 0; r < 4; ++r) acc[fg][r] = 0.f;
#pragma unroll
        for (int kc = 0; kc < 4; ++kc)
#pragma unroll
            for (int fg = 0; fg < 4; ++fg)
                acc[fg] = __builtin_amdgcn_mfma_f32_16x16x32_bf16(
                    afr[kc], bfr[kc][fg], acc[fg], 0, 0, 0);
#pragma unroll
        for (int fg = 0; fg < 4; ++fg)
#pragma unroll
            for (int r = 0; r < 4; ++r)
                h1[(size_t)(tile * 16 + quad * 4 + r) * H1F + fg * 16 + col] =
                    f2us(acc[fg][r]);
    } else {
        // f32 fallback: old shfl-broadcast algorithm, 16 nodes serial per wave
        const float* wfp = (const float*)W1;
        for (int i = 0; i < 16; ++i) {
            int n = tile * 16 + i;
            const float2* xr = (const float2*)((const float*)x + (size_t)n * F_IN);
            float2 my = xr[lane];
            float acc = 0.f;
#pragma unroll 16
            for (int k = 0; k < 64; ++k) {
                float x0 = __shfl(my.x, k, 64);
                float x1 = __shfl(my.y, k, 64);
                acc += x0 * wfp[(2 * k) * H1F + lane];
                acc += x1 * wfp[(2 * k + 1) * H1F + lane];
            }
            h1[(size_t)n * H1F + lane] = f2us(acc);
        }
    }
}

// ---------------- fused agg1 + bias/ReLU + GEMM2 -> h2(bf16) ; wave per node ----------------
__global__ void k_agg1gemm2(const unsigned short* __restrict__ h1,
                            const float* __restrict__ dinv,
                            const int* __restrict__ rowptr, const int* __restrict__ csr,
                            const void* __restrict__ b1, const void* __restrict__ W2,
                            unsigned short* __restrict__ h2, const int* __restrict__ flags) {
    int n    = (blockIdx.x * blockDim.x + threadIdx.x) >> 6;
    int lane = threadIdx.x & 63;
    if (n >= N_NODES) return;
    int beg = rowptr[n], end = rowptr[n + 1];
    float dn  = dinv[n];
    float acc = dn * us2f(h1[(size_t)n * H1F + lane]);  // self-loop
    int e = beg;
    for (; e + 3 < end; e += 4) {                       // 4-deep MLP
        int s0 = csr[e], s1 = csr[e + 1], s2 = csr[e + 2], s3 = csr[e + 3];
        float w0 = dinv[s0], w1 = dinv[s1], w2 = dinv[s2], w3 = dinv[s3];
        unsigned short v0 = h1[(size_t)s0 * H1F + lane];
        unsigned short v1 = h1[(size_t)s1 * H1F + lane];
        unsigned short v2 = h1[(size_t)s2 * H1F + lane];
        unsigned short v3 = h1[(size_t)s3 * H1F + lane];
        acc += w0 * us2f(v0) + w1 * us2f(v1) + w2 * us2f(v2) + w3 * us2f(v3);
    }
    for (; e < end; ++e) {
        int s = csr[e];
        acc += dinv[s] * us2f(h1[(size_t)s * H1F + lane]);
    }
    acc *= dn;                                          // agg1[n][lane]
    int isbf = flags[1];
    float bv = isbf ? b2f(((const __hip_bfloat16*)b1)[lane]) : ((const float*)b1)[lane];
    float v  = fmaxf(acc + bv, 0.f);                    // relu(agg1 + b1)
    // h2[f] = sum_k v_k * W2[k][f] ; lane = f + 32*h, k-range split by h
    int f = lane & 31, h = lane >> 5;
    float part = 0.f;
    if (isbf) {
        const __hip_bfloat16* w = (const __hip_bfloat16*)W2;
#pragma unroll
        for (int j = 0; j < 32; ++j) {
            int k = h * 32 + j;
            part += __shfl(v, k, 64) * b2f(w[k * H2F + f]);
        }
    } else {
        const float* w = (const float*)W2;
#pragma unroll
        for (int j = 0; j < 32; ++j) {
            int k = h * 32 + j;
            part += __shfl(v, k, 64) * w[k * H2F + f];
        }
    }
    part += __shfl(part, lane ^ 32, 64);                // combine halves
    if (h == 0) h2[(size_t)n * H2F + f] = f2us(part);
}

// ---------------- fused agg2 + final MLP -> out ; half-wave per node ----------------
__global__ void GCN_51737176048479_kernel(const unsigned short* __restrict__ h2,
                                          const float* __restrict__ dinv,
                                          const int* __restrict__ rowptr,
                                          const int* __restrict__ csr,
                                          const void* __restrict__ b2v,
                                          const void* __restrict__ Wf,
                                          const void* __restrict__ bfv,
                                          const void* __restrict__ Wo,
                                          const void* __restrict__ bov,
                                          void* __restrict__ out,
                                          const int* __restrict__ flags) {
    int tid = blockIdx.x * blockDim.x + threadIdx.x;
    int n   = tid >> 5;
    int f   = threadIdx.x & 31;
    if (n >= N_NODES) return;
    int isbf = flags[1];
    int beg = rowptr[n], end = rowptr[n + 1];
    float dn = dinv[n];
    float ar = dn * us2f(h2[(size_t)n * H2F + f]);
    int e = beg;
    for (; e + 3 < end; e += 4) {
        int s0 = csr[e], s1 = csr[e + 1], s2 = csr[e + 2], s3 = csr[e + 3];
        float w0 = dinv[s0], w1 = dinv[s1], w2 = dinv[s2], w3 = dinv[s3];
        unsigned short v0 = h2[(size_t)s0 * H2F + f];
        unsigned short v1 = h2[(size_t)s1 * H2F + f];
        unsigned short v2 = h2[(size_t)s2 * H2F + f];
        unsigned short v3 = h2[(size_t)s3 * H2F + f];
        ar += w0 * us2f(v0) + w1 * us2f(v1) + w2 * us2f(v2) + w3 * us2f(v3);
    }
    for (; e < end; ++e) {
        int s = csr[e];
        ar += dinv[s] * us2f(h2[(size_t)s * H2F + f]);
    }
    ar = ar * dn + ld(b2v, f, isbf);                    // conv2 out (no relu)
    float acc1 = 0.f;
#pragma unroll
    for (int k = 0; k < H2F; ++k)
        acc1 += __shfl(ar, k, 32) * ld(Wf, (size_t)k * H2F + f, isbf);
    float u = fmaxf(acc1 + ld(bfv, f, isbf), 0.f);
    float acc2 = 0.f;
#pragma unroll
    for (int k = 0; k < H2F; ++k)
        acc2 += __shfl(u, k, 32) * ld(Wo, (size_t)k * NCLS + f, isbf);
    float r = acc2 + ld(bov, f, isbf);
    size_t oi = (size_t)n * NCLS + f;
    if (isbf) ((__hip_bfloat16*)out)[oi] = __float2bfloat16(r);
    else      ((float*)out)[oi] = r;
}

extern "C" void kernel_launch(void* const* d_in, const int* in_sizes, int n_in,
                              void* d_out, int out_size, void* d_ws, size_t ws_size,
                              hipStream_t stream) {
    const void* x  = d_in[0];
    const int*  ei = (const int*)d_in[1];
    const void* W1 = d_in[2];
    const void* b1 = d_in[3];
    const void* W2 = d_in[4];
    const void* b2 = d_in[5];
    const void* Wf = d_in[6];
    const void* bf = d_in[7];
    const void* Wo = d_in[8];
    const void* bo = d_in[9];

    // workspace (peak ~48 MB):
    //  deg @0 | rowptr @512K | dinv @1M | flags @1.4M | partial @1.41M | chunkoff @1.42M
    //  aux @2M (12.8M) | csr @15M (12.8M) | h1 @28M (12.8M bf16) | h2 @41M (6.4M bf16)
    char* ws = (char*)d_ws;
    int*            deg      = (int*)  (ws + 0);
    int*            rowptr   = (int*)  (ws + (512u  << 10));
    float*          dinv     = (float*)(ws + (1024u << 10));
    int*            flags    = (int*)  (ws + (1434u << 10));
    int*            partial  = (int*)  (ws + (1444u << 10));
    int*            chunkoff = (int*)  (ws + (1454u << 10));
    int*            aux      = (int*)  (ws + (2u  << 20));
    int*            csr      = (int*)  (ws + (15u << 20));
    unsigned short* h1       = (unsigned short*)(ws + (28u << 20));
    unsigned short* h2       = (unsigned short*)(ws + (41u << 20));

    const int B = 256;

    k_detect<<<1, 64, 0, stream>>>(x, ei, flags);
    hipMemsetAsync(deg, 0, N_NODES * sizeof(int), stream);
    k_count<<<(N_EDGES / 4 + B - 1) / B, B, 0, stream>>>(ei, deg, aux, flags);
    k_dinv<<<(N_NODES + B - 1) / B, B, 0, stream>>>(deg, dinv);
    k_scanA<<<SCAN_CHUNKS, SCAN_BLOCK, 0, stream>>>(deg, partial);
    k_scanB<<<1, 64, 0, stream>>>(partial, chunkoff);
    k_scanC<<<SCAN_CHUNKS, SCAN_BLOCK, 0, stream>>>(deg, chunkoff, rowptr);
    k_scatter<<<(N_EDGES / 4 + B - 1) / B, B, 0, stream>>>(ei, aux, rowptr, csr, flags);

    k_gemm1<<<(NTILES * 64 + B - 1) / B, B, 0, stream>>>(x, W1, h1, flags);
    k_agg1gemm2<<<(N_NODES * 64 + B - 1) / B, B, 0, stream>>>(h1, dinv, rowptr, csr,
                                                              b1, W2, h2, flags);
    GCN_51737176048479_kernel<<<(N_NODES * 32 + B - 1) / B, B, 0, stream>>>(
        h2, dinv, rowptr, csr, b2, Wf, bf, Wo, bo, d_out, flags);
}

// Round 10
// 693.697 us; speedup vs baseline: 1.0029x; 1.0029x over previous
//
#include <hip/hip_runtime.h>
#include <hip/hip_bf16.h>

#define N_NODES 100000
#define N_EDGES 3200000
#define F_IN    128
#define H1F     64
#define H2F     32
#define NCLS    32
#define SCAN_BLOCK 1024
#define SCAN_CHUNKS ((N_NODES + SCAN_BLOCK - 1) / SCAN_BLOCK)   // 98
#define NTILES (N_NODES / 16)                                   // 6250 exact

typedef __attribute__((ext_vector_type(8))) short bf16x8;
typedef __attribute__((ext_vector_type(4))) float f32x4;

static __device__ __forceinline__ float b2f(__hip_bfloat16 v) {
    return __bfloat162float(v);
}
static __device__ __forceinline__ float us2f(unsigned short u) {
    return __uint_as_float(((unsigned)u) << 16);
}
static __device__ __forceinline__ unsigned short f2us(float f) {
    __hip_bfloat16 h = __float2bfloat16(f);
    return *(unsigned short*)&h;
}
static __device__ __forceinline__ float ld(const void* p, size_t i, int isbf) {
    return isbf ? b2f(((const __hip_bfloat16*)p)[i]) : ((const float*)p)[i];
}

// flags[0] = edge_index is int64 ; flags[1] = float tensors are bf16

__global__ void k_detect(const void* xbuf, const void* eibuf, int* flags) {
    if (threadIdx.x != 0 || blockIdx.x != 0) return;
    const unsigned* ew = (const unsigned*)eibuf;
    int z = 0;
    for (int k = 0; k < 256; ++k) z += (ew[2 * k + 1] == 0u) ? 1 : 0;
    flags[0] = (z >= 200) ? 1 : 0;
    const unsigned* xw = (const unsigned*)xbuf;
    int inr = 0;
    for (int k = 0; k < 256; ++k) {
        unsigned fb = (xw[k] & 0xFFFFu) << 16;
        float a = fabsf(__uint_as_float(fb));
        inr += (a >= 1e-4f && a <= 20.0f) ? 1 : 0;
    }
    flags[1] = (inr >= 160) ? 1 : 0;
}

// ---------- pack W1 into MFMA B-fragment order ----------
// W1p[((kc*4+fg)*64 + lane)*8 + j] = W1[(kc*32 + quad*8 + j)*H1F + fg*16 + col]
__global__ void k_packW1(const unsigned short* __restrict__ W1,
                         unsigned short* __restrict__ W1p) {
    int t = blockIdx.x * blockDim.x + threadIdx.x;      // 8192 threads
    if (t >= F_IN * H1F) return;
    int j    = t & 7;
    int lane = (t >> 3) & 63;
    int fg   = (t >> 9) & 3;
    int kc   = t >> 11;
    int quad = lane >> 4, col = lane & 15;
    W1p[t] = W1[(kc * 32 + quad * 8 + j) * H1F + fg * 16 + col];
}

// histogram + per-edge rank (aux) in ONE pass; 4 edges/thread, int4 loads
__global__ void k_count(const int* __restrict__ ei, int* __restrict__ deg,
                        int* __restrict__ aux, const int* __restrict__ flags) {
    int t = blockIdx.x * blockDim.x + threadIdx.x;
    int e0 = t * 4;
    if (e0 >= N_EDGES) return;
    int d[4];
    if (flags[0]) {
        const int4* p = (const int4*)(ei + 2 * (size_t)(N_EDGES + e0));
        int4 a = p[0], b = p[1];
        d[0] = a.x; d[1] = a.z; d[2] = b.x; d[3] = b.z;
    } else {
        int4 a = *(const int4*)(ei + (size_t)N_EDGES + e0);
        d[0] = a.x; d[1] = a.y; d[2] = a.z; d[3] = a.w;
    }
    int p0 = ((unsigned)d[0] < N_NODES) ? atomicAdd(&deg[d[0]], 1) : 0;
    int p1 = ((unsigned)d[1] < N_NODES) ? atomicAdd(&deg[d[1]], 1) : 0;
    int p2 = ((unsigned)d[2] < N_NODES) ? atomicAdd(&deg[d[2]], 1) : 0;
    int p3 = ((unsigned)d[3] < N_NODES) ? atomicAdd(&deg[d[3]], 1) : 0;
    *(int4*)(aux + e0) = make_int4(p0, p1, p2, p3);
}

__global__ void k_dinv(const int* __restrict__ deg, float* __restrict__ dinv) {
    int i = blockIdx.x * blockDim.x + threadIdx.x;
    if (i < N_NODES) dinv[i] = rsqrtf((float)deg[i] + 1.0f);  // +1 self-loop
}

// ---------- 3-phase exclusive scan of deg -> rowptr ----------
__global__ void k_scanA(const int* __restrict__ deg, int* __restrict__ partial) {
    __shared__ int red[16];
    int b = blockIdx.x, t = threadIdx.x;
    int i = b * SCAN_BLOCK + t;
    int v = (i < N_NODES) ? deg[i] : 0;
    for (int off = 32; off; off >>= 1) v += __shfl_down(v, off, 64);
    if ((t & 63) == 0) red[t >> 6] = v;
    __syncthreads();
    if (t == 0) {
        int s = 0;
        for (int k = 0; k < 16; ++k) s += red[k];
        partial[b] = s;
    }
}

__global__ void k_scanB(const int* __restrict__ partial, int* __restrict__ chunkoff) {
    if (threadIdx.x != 0 || blockIdx.x != 0) return;
    int run = 0;
    for (int b = 0; b < SCAN_CHUNKS; ++b) { chunkoff[b] = run; run += partial[b]; }
}

__global__ void k_scanC(const int* __restrict__ deg, const int* __restrict__ chunkoff,
                        int* __restrict__ rowptr) {
    __shared__ int wsum[16];
    int b = blockIdx.x, t = threadIdx.x, lane = t & 63, w = t >> 6;
    int i = b * SCAN_BLOCK + t;
    int v = (i < N_NODES) ? deg[i] : 0;
    for (int off = 1; off < 64; off <<= 1) {
        int u = __shfl_up(v, off, 64);
        if (lane >= off) v += u;
    }
    if (lane == 63) wsum[w] = v;
    __syncthreads();
    if (t == 0) {
        int run = 0;
        for (int k = 0; k < 16; ++k) { int s = wsum[k]; wsum[k] = run; run += s; }
    }
    __syncthreads();
    int incl = v + wsum[w] + chunkoff[b];
    if (i < N_NODES) rowptr[i + 1] = incl;
    if (b == 0 && t == 0) rowptr[0] = 0;
}

// atomic-free CSR fill using precomputed ranks
__global__ void k_scatter(const int* __restrict__ ei, const int* __restrict__ aux,
                          const int* __restrict__ rowptr, int* __restrict__ csr,
                          const int* __restrict__ flags) {
    int t = blockIdx.x * blockDim.x + threadIdx.x;
    int e0 = t * 4;
    if (e0 >= N_EDGES) return;
    int s[4], d[4];
    if (flags[0]) {
        const int4* ps = (const int4*)(ei + 2 * (size_t)e0);
        int4 a = ps[0], b = ps[1];
        s[0] = a.x; s[1] = a.z; s[2] = b.x; s[3] = b.z;
        const int4* pd = (const int4*)(ei + 2 * (size_t)(N_EDGES + e0));
        int4 c = pd[0], g = pd[1];
        d[0] = c.x; d[1] = c.z; d[2] = g.x; d[3] = g.z;
    } else {
        int4 a = *(const int4*)(ei + (size_t)e0);
        s[0] = a.x; s[1] = a.y; s[2] = a.z; s[3] = a.w;
        int4 c = *(const int4*)(ei + (size_t)N_EDGES + e0);
        d[0] = c.x; d[1] = c.y; d[2] = c.z; d[3] = c.w;
    }
    int4 av = *(const int4*)(aux + e0);
    int a4[4] = { av.x, av.y, av.z, av.w };
#pragma unroll
    for (int j = 0; j < 4; ++j) {
        if ((unsigned)s[j] < N_NODES && (unsigned)d[j] < N_NODES)
            csr[rowptr[d[j]] + a4[j]] = s[j];
    }
}

// ---------------- GEMM1 via MFMA + packed W1 ; wave per 16-node tile ----------------
// A-frag: A[m=lane&15][k=quad*8+j]  B-frag from W1p (contiguous 16B per lane)
// C/D: col=lane&15, row=quad*4+reg   (m89-verified; round-9 output was correct)
__global__ void k_gemm1(const void* __restrict__ x, const void* __restrict__ W1,
                        const unsigned short* __restrict__ W1p,
                        unsigned short* __restrict__ h1, const int* __restrict__ flags) {
    int tile = (blockIdx.x * blockDim.x + threadIdx.x) >> 6;
    int lane = threadIdx.x & 63;
    if (tile >= NTILES) return;
    int col = lane & 15, quad = lane >> 4;

    if (flags[1]) {
        const short* xp = (const short*)x;
        // A fragments (16B contiguous per lane per K-chunk)
        bf16x8 afr[4];
#pragma unroll
        for (int kc = 0; kc < 4; ++kc)
            afr[kc] = *(const bf16x8*)(xp + (size_t)(tile * 16 + col) * F_IN + kc * 32 + quad * 8);
        // B fragments: one 16B vector load each from packed W1
        bf16x8 bfr[4][4];
#pragma unroll
        for (int kc = 0; kc < 4; ++kc)
#pragma unroll
            for (int fg = 0; fg < 4; ++fg)
                bfr[kc][fg] = *(const bf16x8*)(W1p + (((kc * 4 + fg) * 64 + lane) * 8));
        f32x4 acc[4];
#pragma unroll
        for (int fg = 0; fg < 4; ++fg)
#pragma unroll
            for (int r = 0; r < 4; ++r) acc[fg][r] = 0.f;
#pragma unroll
        for (int kc = 0; kc < 4; ++kc)
#pragma unroll
            for (int fg = 0; fg < 4; ++fg)
                acc[fg] = __builtin_amdgcn_mfma_f32_16x16x32_bf16(
                    afr[kc], bfr[kc][fg], acc[fg], 0, 0, 0);
#pragma unroll
        for (int fg = 0; fg < 4; ++fg)
#pragma unroll
            for (int r = 0; r < 4; ++r)
                h1[(size_t)(tile * 16 + quad * 4 + r) * H1F + fg * 16 + col] =
                    f2us(acc[fg][r]);
    } else {
        // f32 fallback: shfl-broadcast, 16 nodes serial per wave
        const float* wfp = (const float*)W1;
        for (int i = 0; i < 16; ++i) {
            int n = tile * 16 + i;
            const float2* xr = (const float2*)((const float*)x + (size_t)n * F_IN);
            float2 my = xr[lane];
            float acc = 0.f;
#pragma unroll 16
            for (int k = 0; k < 64; ++k) {
                float x0 = __shfl(my.x, k, 64);
                float x1 = __shfl(my.y, k, 64);
                acc += x0 * wfp[(2 * k) * H1F + lane];
                acc += x1 * wfp[(2 * k + 1) * H1F + lane];
            }
            h1[(size_t)n * H1F + lane] = f2us(acc);
        }
    }
}

// ---------------- fused agg1 + bias/ReLU + GEMM2 -> h2(bf16) ; wave per node ----------------
__global__ void k_agg1gemm2(const unsigned short* __restrict__ h1,
                            const float* __restrict__ dinv,
                            const int* __restrict__ rowptr, const int* __restrict__ csr,
                            const void* __restrict__ b1, const void* __restrict__ W2,
                            unsigned short* __restrict__ h2, const int* __restrict__ flags) {
    int n    = (blockIdx.x * blockDim.x + threadIdx.x) >> 6;
    int lane = threadIdx.x & 63;
    if (n >= N_NODES) return;
    int beg = rowptr[n], end = rowptr[n + 1];
    float dn  = dinv[n];
    float acc = dn * us2f(h1[(size_t)n * H1F + lane]);  // self-loop
    int e = beg;
    for (; e + 3 < end; e += 4) {                       // 4-deep MLP
        int s0 = csr[e], s1 = csr[e + 1], s2 = csr[e + 2], s3 = csr[e + 3];
        float w0 = dinv[s0], w1 = dinv[s1], w2 = dinv[s2], w3 = dinv[s3];
        unsigned short v0 = h1[(size_t)s0 * H1F + lane];
        unsigned short v1 = h1[(size_t)s1 * H1F + lane];
        unsigned short v2 = h1[(size_t)s2 * H1F + lane];
        unsigned short v3 = h1[(size_t)s3 * H1F + lane];
        acc += w0 * us2f(v0) + w1 * us2f(v1) + w2 * us2f(v2) + w3 * us2f(v3);
    }
    for (; e < end; ++e) {
        int s = csr[e];
        acc += dinv[s] * us2f(h1[(size_t)s * H1F + lane]);
    }
    acc *= dn;                                          // agg1[n][lane]
    int isbf = flags[1];
    float bv = isbf ? b2f(((const __hip_bfloat16*)b1)[lane]) : ((const float*)b1)[lane];
    float v  = fmaxf(acc + bv, 0.f);                    // relu(agg1 + b1)
    int f = lane & 31, h = lane >> 5;
    float part = 0.f;
    if (isbf) {
        const __hip_bfloat16* w = (const __hip_bfloat16*)W2;
#pragma unroll
        for (int j = 0; j < 32; ++j) {
            int k = h * 32 + j;
            part += __shfl(v, k, 64) * b2f(w[k * H2F + f]);
        }
    } else {
        const float* w = (const float*)W2;
#pragma unroll
        for (int j = 0; j < 32; ++j) {
            int k = h * 32 + j;
            part += __shfl(v, k, 64) * w[k * H2F + f];
        }
    }
    part += __shfl(part, lane ^ 32, 64);                // combine halves
    if (h == 0) h2[(size_t)n * H2F + f] = f2us(part);
}

// ---------------- fused agg2 + final MLP -> out ; half-wave per node ----------------
__global__ void GCN_51737176048479_kernel(const unsigned short* __restrict__ h2,
                                          const float* __restrict__ dinv,
                                          const int* __restrict__ rowptr,
                                          const int* __restrict__ csr,
                                          const void* __restrict__ b2v,
                                          const void* __restrict__ Wf,
                                          const void* __restrict__ bfv,
                                          const void* __restrict__ Wo,
                                          const void* __restrict__ bov,
                                          void* __restrict__ out,
                                          const int* __restrict__ flags) {
    int tid = blockIdx.x * blockDim.x + threadIdx.x;
    int n   = tid >> 5;
    int f   = threadIdx.x & 31;
    if (n >= N_NODES) return;
    int isbf = flags[1];
    int beg = rowptr[n], end = rowptr[n + 1];
    float dn = dinv[n];
    float ar = dn * us2f(h2[(size_t)n * H2F + f]);
    int e = beg;
    for (; e + 3 < end; e += 4) {
        int s0 = csr[e], s1 = csr[e + 1], s2 = csr[e + 2], s3 = csr[e + 3];
        float w0 = dinv[s0], w1 = dinv[s1], w2 = dinv[s2], w3 = dinv[s3];
        unsigned short v0 = h2[(size_t)s0 * H2F + f];
        unsigned short v1 = h2[(size_t)s1 * H2F + f];
        unsigned short v2 = h2[(size_t)s2 * H2F + f];
        unsigned short v3 = h2[(size_t)s3 * H2F + f];
        ar += w0 * us2f(v0) + w1 * us2f(v1) + w2 * us2f(v2) + w3 * us2f(v3);
    }
    for (; e < end; ++e) {
        int s = csr[e];
        ar += dinv[s] * us2f(h2[(size_t)s * H2F + f]);
    }
    ar = ar * dn + ld(b2v, f, isbf);                    // conv2 out (no relu)
    float acc1 = 0.f;
#pragma unroll
    for (int k = 0; k < H2F; ++k)
        acc1 += __shfl(ar, k, 32) * ld(Wf, (size_t)k * H2F + f, isbf);
    float u = fmaxf(acc1 + ld(bfv, f, isbf), 0.f);
    float acc2 = 0.f;
#pragma unroll
    for (int k = 0; k < H2F; ++k)
        acc2 += __shfl(u, k, 32) * ld(Wo, (size_t)k * NCLS + f, isbf);
    float r = acc2 + ld(bov, f, isbf);
    size_t oi = (size_t)n * NCLS + f;
    if (isbf) ((__hip_bfloat16*)out)[oi] = __float2bfloat16(r);
    else      ((float*)out)[oi] = r;
}

extern "C" void kernel_launch(void* const* d_in, const int* in_sizes, int n_in,
                              void* d_out, int out_size, void* d_ws, size_t ws_size,
                              hipStream_t stream) {
    const void* x  = d_in[0];
    const int*  ei = (const int*)d_in[1];
    const void* W1 = d_in[2];
    const void* b1 = d_in[3];
    const void* W2 = d_in[4];
    const void* b2 = d_in[5];
    const void* Wf = d_in[6];
    const void* bf = d_in[7];
    const void* Wo = d_in[8];
    const void* bo = d_in[9];

    // workspace (peak ~48 MB):
    //  deg @0 | rowptr @512K | dinv @1M | flags @1.4M | partial @1.41M | chunkoff @1.42M
    //  W1p @1.5M (16K) | aux @2M (12.8M) | csr @15M (12.8M)
    //  h1 @28M (12.8M bf16) | h2 @41M (6.4M bf16)
    char* ws = (char*)d_ws;
    int*            deg      = (int*)  (ws + 0);
    int*            rowptr   = (int*)  (ws + (512u  << 10));
    float*          dinv     = (float*)(ws + (1024u << 10));
    int*            flags    = (int*)  (ws + (1434u << 10));
    int*            partial  = (int*)  (ws + (1444u << 10));
    int*            chunkoff = (int*)  (ws + (1454u << 10));
    unsigned short* W1p      = (unsigned short*)(ws + (1536u << 10));
    int*            aux      = (int*)  (ws + (2u  << 20));
    int*            csr      = (int*)  (ws + (15u << 20));
    unsigned short* h1       = (unsigned short*)(ws + (28u << 20));
    unsigned short* h2       = (unsigned short*)(ws + (41u << 20));

    const int B = 256;

    k_detect<<<1, 64, 0, stream>>>(x, ei, flags);
    hipMemsetAsync(deg, 0, N_NODES * sizeof(int), stream);
    k_packW1<<<(F_IN * H1F + B - 1) / B, B, 0, stream>>>((const unsigned short*)W1, W1p);
    k_count<<<(N_EDGES / 4 + B - 1) / B, B, 0, stream>>>(ei, deg, aux, flags);
    k_dinv<<<(N_NODES + B - 1) / B, B, 0, stream>>>(deg, dinv);
    k_scanA<<<SCAN_CHUNKS, SCAN_BLOCK, 0, stream>>>(deg, partial);
    k_scanB<<<1, 64, 0, stream>>>(partial, chunkoff);
    k_scanC<<<SCAN_CHUNKS, SCAN_BLOCK, 0, stream>>>(deg, chunkoff, rowptr);
    k_scatter<<<(N_EDGES / 4 + B - 1) / B, B, 0, stream>>>(ei, aux, rowptr, csr, flags);

    k_gemm1<<<(NTILES * 64 + B - 1) / B, B, 0, stream>>>(x, W1, W1p, h1, flags);
    k_agg1gemm2<<<(N_NODES * 64 + B - 1) / B, B, 0, stream>>>(h1, dinv, rowptr, csr,
                                                              b1, W2, h2, flags);
    GCN_51737176048479_kernel<<<(N_NODES * 32 + B - 1) / B, B, 0, stream>>>(
        h2, dinv, rowptr, csr, b2, Wf, bf, Wo, bo, d_out, flags);
}

// Round 11
// 693.189 us; speedup vs baseline: 1.0037x; 1.0007x over previous
//
#include <hip/hip_runtime.h>
#include <hip/hip_bf16.h>

#define N_NODES 100000
#define N_EDGES 3200000
#define F_IN    128
#define H1F     64
#define H2F     32
#define NCLS    32
#define SCAN_BLOCK 1024
#define SCAN_CHUNKS ((N_NODES + SCAN_BLOCK - 1) / SCAN_BLOCK)   // 98
#define NTILES (N_NODES / 16)                                   // 6250 exact

typedef __attribute__((ext_vector_type(8))) short bf16x8;
typedef __attribute__((ext_vector_type(4))) float f32x4;

static __device__ __forceinline__ float b2f(__hip_bfloat16 v) {
    return __bfloat162float(v);
}
static __device__ __forceinline__ float us2f(unsigned short u) {
    return __uint_as_float(((unsigned)u) << 16);
}
static __device__ __forceinline__ unsigned short f2us(float f) {
    __hip_bfloat16 h = __float2bfloat16(f);
    return *(unsigned short*)&h;
}
static __device__ __forceinline__ float ld(const void* p, size_t i, int isbf) {
    return isbf ? b2f(((const __hip_bfloat16*)p)[i]) : ((const float*)p)[i];
}

// flags[0] = edge_index is int64 ; flags[1] = float tensors are bf16

__global__ void k_detect(const void* xbuf, const void* eibuf, int* flags) {
    if (threadIdx.x != 0 || blockIdx.x != 0) return;
    const unsigned* ew = (const unsigned*)eibuf;
    int z = 0;
    for (int k = 0; k < 256; ++k) z += (ew[2 * k + 1] == 0u) ? 1 : 0;
    flags[0] = (z >= 200) ? 1 : 0;
    const unsigned* xw = (const unsigned*)xbuf;
    int inr = 0;
    for (int k = 0; k < 256; ++k) {
        unsigned fb = (xw[k] & 0xFFFFu) << 16;
        float a = fabsf(__uint_as_float(fb));
        inr += (a >= 1e-4f && a <= 20.0f) ? 1 : 0;
    }
    flags[1] = (inr >= 160) ? 1 : 0;
}

// ---------- pack W1 into MFMA B-fragment order ----------
// W1p[((kc*4+fg)*64 + lane)*8 + j] = W1[(kc*32 + quad*8 + j)*H1F + fg*16 + col]
__global__ void k_packW1(const unsigned short* __restrict__ W1,
                         unsigned short* __restrict__ W1p) {
    int t = blockIdx.x * blockDim.x + threadIdx.x;      // 8192 threads
    if (t >= F_IN * H1F) return;
    int j    = t & 7;
    int lane = (t >> 3) & 63;
    int fg   = (t >> 9) & 3;
    int kc   = t >> 11;
    int quad = lane >> 4, col = lane & 15;
    W1p[t] = W1[(kc * 32 + quad * 8 + j) * H1F + fg * 16 + col];
}

// histogram + per-edge rank (aux) in ONE pass; 4 edges/thread, int4 loads
__global__ void k_count(const int* __restrict__ ei, int* __restrict__ deg,
                        int* __restrict__ aux, const int* __restrict__ flags) {
    int t = blockIdx.x * blockDim.x + threadIdx.x;
    int e0 = t * 4;
    if (e0 >= N_EDGES) return;
    int d[4];
    if (flags[0]) {
        const int4* p = (const int4*)(ei + 2 * (size_t)(N_EDGES + e0));
        int4 a = p[0], b = p[1];
        d[0] = a.x; d[1] = a.z; d[2] = b.x; d[3] = b.z;
    } else {
        int4 a = *(const int4*)(ei + (size_t)N_EDGES + e0);
        d[0] = a.x; d[1] = a.y; d[2] = a.z; d[3] = a.w;
    }
    int p0 = ((unsigned)d[0] < N_NODES) ? atomicAdd(&deg[d[0]], 1) : 0;
    int p1 = ((unsigned)d[1] < N_NODES) ? atomicAdd(&deg[d[1]], 1) : 0;
    int p2 = ((unsigned)d[2] < N_NODES) ? atomicAdd(&deg[d[2]], 1) : 0;
    int p3 = ((unsigned)d[3] < N_NODES) ? atomicAdd(&deg[d[3]], 1) : 0;
    *(int4*)(aux + e0) = make_int4(p0, p1, p2, p3);
}

__global__ void k_dinv(const int* __restrict__ deg, float* __restrict__ dinv) {
    int i = blockIdx.x * blockDim.x + threadIdx.x;
    if (i < N_NODES) dinv[i] = rsqrtf((float)deg[i] + 1.0f);  // +1 self-loop
}

// ---------- 3-phase exclusive scan of deg -> rowptr ----------
__global__ void k_scanA(const int* __restrict__ deg, int* __restrict__ partial) {
    __shared__ int red[16];
    int b = blockIdx.x, t = threadIdx.x;
    int i = b * SCAN_BLOCK + t;
    int v = (i < N_NODES) ? deg[i] : 0;
    for (int off = 32; off; off >>= 1) v += __shfl_down(v, off, 64);
    if ((t & 63) == 0) red[t >> 6] = v;
    __syncthreads();
    if (t == 0) {
        int s = 0;
        for (int k = 0; k < 16; ++k) s += red[k];
        partial[b] = s;
    }
}

__global__ void k_scanB(const int* __restrict__ partial, int* __restrict__ chunkoff) {
    if (threadIdx.x != 0 || blockIdx.x != 0) return;
    int run = 0;
    for (int b = 0; b < SCAN_CHUNKS; ++b) { chunkoff[b] = run; run += partial[b]; }
}

__global__ void k_scanC(const int* __restrict__ deg, const int* __restrict__ chunkoff,
                        int* __restrict__ rowptr) {
    __shared__ int wsum[16];
    int b = blockIdx.x, t = threadIdx.x, lane = t & 63, w = t >> 6;
    int i = b * SCAN_BLOCK + t;
    int v = (i < N_NODES) ? deg[i] : 0;
    for (int off = 1; off < 64; off <<= 1) {
        int u = __shfl_up(v, off, 64);
        if (lane >= off) v += u;
    }
    if (lane == 63) wsum[w] = v;
    __syncthreads();
    if (t == 0) {
        int run = 0;
        for (int k = 0; k < 16; ++k) { int s = wsum[k]; wsum[k] = run; run += s; }
    }
    __syncthreads();
    int incl = v + wsum[w] + chunkoff[b];
    if (i < N_NODES) rowptr[i + 1] = incl;
    if (b == 0 && t == 0) rowptr[0] = 0;
}

// atomic-free CSR fill using precomputed ranks
__global__ void k_scatter(const int* __restrict__ ei, const int* __restrict__ aux,
                          const int* __restrict__ rowptr, int* __restrict__ csr,
                          const int* __restrict__ flags) {
    int t = blockIdx.x * blockDim.x + threadIdx.x;
    int e0 = t * 4;
    if (e0 >= N_EDGES) return;
    int s[4], d[4];
    if (flags[0]) {
        const int4* ps = (const int4*)(ei + 2 * (size_t)e0);
        int4 a = ps[0], b = ps[1];
        s[0] = a.x; s[1] = a.z; s[2] = b.x; s[3] = b.z;
        const int4* pd = (const int4*)(ei + 2 * (size_t)(N_EDGES + e0));
        int4 c = pd[0], g = pd[1];
        d[0] = c.x; d[1] = c.z; d[2] = g.x; d[3] = g.z;
    } else {
        int4 a = *(const int4*)(ei + (size_t)e0);
        s[0] = a.x; s[1] = a.y; s[2] = a.z; s[3] = a.w;
        int4 c = *(const int4*)(ei + (size_t)N_EDGES + e0);
        d[0] = c.x; d[1] = c.y; d[2] = c.z; d[3] = c.w;
    }
    int4 av = *(const int4*)(aux + e0);
    int a4[4] = { av.x, av.y, av.z, av.w };
#pragma unroll
    for (int j = 0; j < 4; ++j) {
        if ((unsigned)s[j] < N_NODES && (unsigned)d[j] < N_NODES)
            csr[rowptr[d[j]] + a4[j]] = s[j];
    }
}

// ---------------- GEMM1 via MFMA + LDS-staged W1p ; 4 tiles per block ----------------
// A-frag: A[m=lane&15][k=quad*8+j]  B-frag: ds_read_b128 from staged W1p
// C/D: col=lane&15, row=quad*4+reg   (verified correct in rounds 9/10)
__global__ void __launch_bounds__(256, 1)
k_gemm1(const void* __restrict__ x, const void* __restrict__ W1,
        const unsigned short* __restrict__ W1p,
        unsigned short* __restrict__ h1, const int* __restrict__ flags) {
    __shared__ unsigned short w1s[F_IN * H1F];          // 16 KB
    int tid  = threadIdx.x;
    int isbf = flags[1];
    if (isbf) {                                         // cooperative stage, coalesced
        const uint4* src = (const uint4*)W1p;
        uint4*       dst = (uint4*)w1s;
#pragma unroll
        for (int k = 0; k < 4; ++k) dst[tid + k * 256] = src[tid + k * 256];
    }
    __syncthreads();

    int wave = tid >> 6, lane = tid & 63;
    int tile = blockIdx.x * 4 + wave;
    if (tile >= NTILES) return;
    int col = lane & 15, quad = lane >> 4;

    if (isbf) {
        const short* xp = (const short*)x;
        bf16x8 afr[4];                                  // 4 independent global loads
#pragma unroll
        for (int kc = 0; kc < 4; ++kc)
            afr[kc] = *(const bf16x8*)(xp + (size_t)(tile * 16 + col) * F_IN + kc * 32 + quad * 8);
        f32x4 acc[4];
#pragma unroll
        for (int fg = 0; fg < 4; ++fg)
#pragma unroll
            for (int r = 0; r < 4; ++r) acc[fg][r] = 0.f;
#pragma unroll
        for (int kc = 0; kc < 4; ++kc)
#pragma unroll
            for (int fg = 0; fg < 4; ++fg) {
                bf16x8 bfr = *(const bf16x8*)(w1s + (((kc * 4 + fg) * 64 + lane) * 8));
                acc[fg] = __builtin_amdgcn_mfma_f32_16x16x32_bf16(
                    afr[kc], bfr, acc[fg], 0, 0, 0);
            }
#pragma unroll
        for (int fg = 0; fg < 4; ++fg)
#pragma unroll
            for (int r = 0; r < 4; ++r)
                h1[(size_t)(tile * 16 + quad * 4 + r) * H1F + fg * 16 + col] =
                    f2us(acc[fg][r]);
    } else {
        // f32 fallback: shfl-broadcast, 16 nodes serial per wave
        const float* wfp = (const float*)W1;
        for (int i = 0; i < 16; ++i) {
            int n = tile * 16 + i;
            const float2* xr = (const float2*)((const float*)x + (size_t)n * F_IN);
            float2 my = xr[lane];
            float acc = 0.f;
#pragma unroll 16
            for (int k = 0; k < 64; ++k) {
                float x0 = __shfl(my.x, k, 64);
                float x1 = __shfl(my.y, k, 64);
                acc += x0 * wfp[(2 * k) * H1F + lane];
                acc += x1 * wfp[(2 * k + 1) * H1F + lane];
            }
            h1[(size_t)n * H1F + lane] = f2us(acc);
        }
    }
}

// ---------------- fused agg1 + bias/ReLU + GEMM2 -> h2(bf16) ; wave per node ----------------
__global__ void k_agg1gemm2(const unsigned short* __restrict__ h1,
                            const float* __restrict__ dinv,
                            const int* __restrict__ rowptr, const int* __restrict__ csr,
                            const void* __restrict__ b1, const void* __restrict__ W2,
                            unsigned short* __restrict__ h2, const int* __restrict__ flags) {
    int n    = (blockIdx.x * blockDim.x + threadIdx.x) >> 6;
    int lane = threadIdx.x & 63;
    if (n >= N_NODES) return;
    int beg = rowptr[n], end = rowptr[n + 1];
    float dn  = dinv[n];
    float acc = dn * us2f(h1[(size_t)n * H1F + lane]);  // self-loop
    int e = beg;
    for (; e + 3 < end; e += 4) {                       // 4-deep MLP
        int s0 = csr[e], s1 = csr[e + 1], s2 = csr[e + 2], s3 = csr[e + 3];
        float w0 = dinv[s0], w1 = dinv[s1], w2 = dinv[s2], w3 = dinv[s3];
        unsigned short v0 = h1[(size_t)s0 * H1F + lane];
        unsigned short v1 = h1[(size_t)s1 * H1F + lane];
        unsigned short v2 = h1[(size_t)s2 * H1F + lane];
        unsigned short v3 = h1[(size_t)s3 * H1F + lane];
        acc += w0 * us2f(v0) + w1 * us2f(v1) + w2 * us2f(v2) + w3 * us2f(v3);
    }
    for (; e < end; ++e) {
        int s = csr[e];
        acc += dinv[s] * us2f(h1[(size_t)s * H1F + lane]);
    }
    acc *= dn;                                          // agg1[n][lane]
    int isbf = flags[1];
    float bv = isbf ? b2f(((const __hip_bfloat16*)b1)[lane]) : ((const float*)b1)[lane];
    float v  = fmaxf(acc + bv, 0.f);                    // relu(agg1 + b1)
    int f = lane & 31, h = lane >> 5;
    float part = 0.f;
    if (isbf) {
        const __hip_bfloat16* w = (const __hip_bfloat16*)W2;
#pragma unroll
        for (int j = 0; j < 32; ++j) {
            int k = h * 32 + j;
            part += __shfl(v, k, 64) * b2f(w[k * H2F + f]);
        }
    } else {
        const float* w = (const float*)W2;
#pragma unroll
        for (int j = 0; j < 32; ++j) {
            int k = h * 32 + j;
            part += __shfl(v, k, 64) * w[k * H2F + f];
        }
    }
    part += __shfl(part, lane ^ 32, 64);                // combine halves
    if (h == 0) h2[(size_t)n * H2F + f] = f2us(part);
}

// ---------------- fused agg2 + final MLP -> out ; half-wave per node ----------------
__global__ void GCN_51737176048479_kernel(const unsigned short* __restrict__ h2,
                                          const float* __restrict__ dinv,
                                          const int* __restrict__ rowptr,
                                          const int* __restrict__ csr,
                                          const void* __restrict__ b2v,
                                          const void* __restrict__ Wf,
                                          const void* __restrict__ bfv,
                                          const void* __restrict__ Wo,
                                          const void* __restrict__ bov,
                                          void* __restrict__ out,
                                          const int* __restrict__ flags) {
    int tid = blockIdx.x * blockDim.x + threadIdx.x;
    int n   = tid >> 5;
    int f   = threadIdx.x & 31;
    if (n >= N_NODES) return;
    int isbf = flags[1];
    int beg = rowptr[n], end = rowptr[n + 1];
    float dn = dinv[n];
    float ar = dn * us2f(h2[(size_t)n * H2F + f]);
    int e = beg;
    for (; e + 3 < end; e += 4) {
        int s0 = csr[e], s1 = csr[e + 1], s2 = csr[e + 2], s3 = csr[e + 3];
        float w0 = dinv[s0], w1 = dinv[s1], w2 = dinv[s2], w3 = dinv[s3];
        unsigned short v0 = h2[(size_t)s0 * H2F + f];
        unsigned short v1 = h2[(size_t)s1 * H2F + f];
        unsigned short v2 = h2[(size_t)s2 * H2F + f];
        unsigned short v3 = h2[(size_t)s3 * H2F + f];
        ar += w0 * us2f(v0) + w1 * us2f(v1) + w2 * us2f(v2) + w3 * us2f(v3);
    }
    for (; e < end; ++e) {
        int s = csr[e];
        ar += dinv[s] * us2f(h2[(size_t)s * H2F + f]);
    }
    ar = ar * dn + ld(b2v, f, isbf);                    // conv2 out (no relu)
    float acc1 = 0.f;
#pragma unroll
    for (int k = 0; k < H2F; ++k)
        acc1 += __shfl(ar, k, 32) * ld(Wf, (size_t)k * H2F + f, isbf);
    float u = fmaxf(acc1 + ld(bfv, f, isbf), 0.f);
    float acc2 = 0.f;
#pragma unroll
    for (int k = 0; k < H2F; ++k)
        acc2 += __shfl(u, k, 32) * ld(Wo, (size_t)k * NCLS + f, isbf);
    float r = acc2 + ld(bov, f, isbf);
    size_t oi = (size_t)n * NCLS + f;
    if (isbf) ((__hip_bfloat16*)out)[oi] = __float2bfloat16(r);
    else      ((float*)out)[oi] = r;
}

extern "C" void kernel_launch(void* const* d_in, const int* in_sizes, int n_in,
                              void* d_out, int out_size, void* d_ws, size_t ws_size,
                              hipStream_t stream) {
    const void* x  = d_in[0];
    const int*  ei = (const int*)d_in[1];
    const void* W1 = d_in[2];
    const void* b1 = d_in[3];
    const void* W2 = d_in[4];
    const void* b2 = d_in[5];
    const void* Wf = d_in[6];
    const void* bf = d_in[7];
    const void* Wo = d_in[8];
    const void* bo = d_in[9];

    // workspace (peak ~48 MB):
    //  deg @0 | rowptr @512K | dinv @1M | flags @1.4M | partial @1.41M | chunkoff @1.42M
    //  W1p @1.5M (16K) | aux @2M (12.8M) | csr @15M (12.8M)
    //  h1 @28M (12.8M bf16) | h2 @41M (6.4M bf16)
    char* ws = (char*)d_ws;
    int*            deg      = (int*)  (ws + 0);
    int*            rowptr   = (int*)  (ws + (512u  << 10));
    float*          dinv     = (float*)(ws + (1024u << 10));
    int*            flags    = (int*)  (ws + (1434u << 10));
    int*            partial  = (int*)  (ws + (1444u << 10));
    int*            chunkoff = (int*)  (ws + (1454u << 10));
    unsigned short* W1p      = (unsigned short*)(ws + (1536u << 10));
    int*            aux      = (int*)  (ws + (2u  << 20));
    int*            csr      = (int*)  (ws + (15u << 20));
    unsigned short* h1       = (unsigned short*)(ws + (28u << 20));
    unsigned short* h2       = (unsigned short*)(ws + (41u << 20));

    const int B = 256;

    k_detect<<<1, 64, 0, stream>>>(x, ei, flags);
    hipMemsetAsync(deg, 0, N_NODES * sizeof(int), stream);
    k_packW1<<<(F_IN * H1F + B - 1) / B, B, 0, stream>>>((const unsigned short*)W1, W1p);
    k_count<<<(N_EDGES / 4 + B - 1) / B, B, 0, stream>>>(ei, deg, aux, flags);
    k_dinv<<<(N_NODES + B - 1) / B, B, 0, stream>>>(deg, dinv);
    k_scanA<<<SCAN_CHUNKS, SCAN_BLOCK, 0, stream>>>(deg, partial);
    k_scanB<<<1, 64, 0, stream>>>(partial, chunkoff);
    k_scanC<<<SCAN_CHUNKS, SCAN_BLOCK, 0, stream>>>(deg, chunkoff, rowptr);
    k_scatter<<<(N_EDGES / 4 + B - 1) / B, B, 0, stream>>>(ei, aux, rowptr, csr, flags);

    k_gemm1<<<(NTILES + 3) / 4, B, 0, stream>>>(x, W1, W1p, h1, flags);
    k_agg1gemm2<<<(N_NODES * 64 + B - 1) / B, B, 0, stream>>>(h1, dinv, rowptr, csr,
                                                              b1, W2, h2, flags);
    GCN_51737176048479_kernel<<<(N_NODES * 32 + B - 1) / B, B, 0, stream>>>(
        h2, dinv, rowptr, csr, b2, Wf, bf, Wo, bo, d_out, flags);
}

// Round 12
// 673.617 us; speedup vs baseline: 1.0328x; 1.0291x over previous
//
#include <hip/hip_runtime.h>
#include <hip/hip_bf16.h>

#define N_NODES 100000
#define N_EDGES 3200000
#define F_IN    128
#define H1F     64
#define H2F     32
#define NCLS    32
#define SCAN_BLOCK 1024
#define SCAN_CHUNKS ((N_NODES + SCAN_BLOCK - 1) / SCAN_BLOCK)   // 98
#define NTILES (N_NODES / 16)                                   // 6250 exact
#define XPAD 132                                                // 128 + 4 shorts: LDS bank de-alias

typedef __attribute__((ext_vector_type(8))) short bf16x8;
typedef __attribute__((ext_vector_type(4))) float f32x4;

static __device__ __forceinline__ float b2f(__hip_bfloat16 v) {
    return __bfloat162float(v);
}
static __device__ __forceinline__ float us2f(unsigned short u) {
    return __uint_as_float(((unsigned)u) << 16);
}
static __device__ __forceinline__ unsigned short f2us(float f) {
    __hip_bfloat16 h = __float2bfloat16(f);
    return *(unsigned short*)&h;
}
static __device__ __forceinline__ float ld(const void* p, size_t i, int isbf) {
    return isbf ? b2f(((const __hip_bfloat16*)p)[i]) : ((const float*)p)[i];
}

// flags[0] = edge_index is int64 ; flags[1] = float tensors are bf16

__global__ void k_detect(const void* xbuf, const void* eibuf, int* flags) {
    if (threadIdx.x != 0 || blockIdx.x != 0) return;
    const unsigned* ew = (const unsigned*)eibuf;
    int z = 0;
    for (int k = 0; k < 256; ++k) z += (ew[2 * k + 1] == 0u) ? 1 : 0;
    flags[0] = (z >= 200) ? 1 : 0;
    const unsigned* xw = (const unsigned*)xbuf;
    int inr = 0;
    for (int k = 0; k < 256; ++k) {
        unsigned fb = (xw[k] & 0xFFFFu) << 16;
        float a = fabsf(__uint_as_float(fb));
        inr += (a >= 1e-4f && a <= 20.0f) ? 1 : 0;
    }
    flags[1] = (inr >= 160) ? 1 : 0;
}

// ---------- pack W1 into MFMA B-fragment order ----------
// W1p[((kc*4+fg)*64 + lane)*8 + j] = W1[(kc*32 + quad*8 + j)*H1F + fg*16 + col]
__global__ void k_packW1(const unsigned short* __restrict__ W1,
                         unsigned short* __restrict__ W1p) {
    int t = blockIdx.x * blockDim.x + threadIdx.x;      // 8192 threads
    if (t >= F_IN * H1F) return;
    int j    = t & 7;
    int lane = (t >> 3) & 63;
    int fg   = (t >> 9) & 3;
    int kc   = t >> 11;
    int quad = lane >> 4, col = lane & 15;
    W1p[t] = W1[(kc * 32 + quad * 8 + j) * H1F + fg * 16 + col];
}

// histogram + per-edge rank (aux) in ONE pass; 4 edges/thread, int4 loads
__global__ void k_count(const int* __restrict__ ei, int* __restrict__ deg,
                        int* __restrict__ aux, const int* __restrict__ flags) {
    int t = blockIdx.x * blockDim.x + threadIdx.x;
    int e0 = t * 4;
    if (e0 >= N_EDGES) return;
    int d[4];
    if (flags[0]) {
        const int4* p = (const int4*)(ei + 2 * (size_t)(N_EDGES + e0));
        int4 a = p[0], b = p[1];
        d[0] = a.x; d[1] = a.z; d[2] = b.x; d[3] = b.z;
    } else {
        int4 a = *(const int4*)(ei + (size_t)N_EDGES + e0);
        d[0] = a.x; d[1] = a.y; d[2] = a.z; d[3] = a.w;
    }
    int p0 = ((unsigned)d[0] < N_NODES) ? atomicAdd(&deg[d[0]], 1) : 0;
    int p1 = ((unsigned)d[1] < N_NODES) ? atomicAdd(&deg[d[1]], 1) : 0;
    int p2 = ((unsigned)d[2] < N_NODES) ? atomicAdd(&deg[d[2]], 1) : 0;
    int p3 = ((unsigned)d[3] < N_NODES) ? atomicAdd(&deg[d[3]], 1) : 0;
    *(int4*)(aux + e0) = make_int4(p0, p1, p2, p3);
}

__global__ void k_dinv(const int* __restrict__ deg, float* __restrict__ dinv) {
    int i = blockIdx.x * blockDim.x + threadIdx.x;
    if (i < N_NODES) dinv[i] = rsqrtf((float)deg[i] + 1.0f);  // +1 self-loop
}

// ---------- 3-phase exclusive scan of deg -> rowptr ----------
__global__ void k_scanA(const int* __restrict__ deg, int* __restrict__ partial) {
    __shared__ int red[16];
    int b = blockIdx.x, t = threadIdx.x;
    int i = b * SCAN_BLOCK + t;
    int v = (i < N_NODES) ? deg[i] : 0;
    for (int off = 32; off; off >>= 1) v += __shfl_down(v, off, 64);
    if ((t & 63) == 0) red[t >> 6] = v;
    __syncthreads();
    if (t == 0) {
        int s = 0;
        for (int k = 0; k < 16; ++k) s += red[k];
        partial[b] = s;
    }
}

__global__ void k_scanB(const int* __restrict__ partial, int* __restrict__ chunkoff) {
    if (threadIdx.x != 0 || blockIdx.x != 0) return;
    int run = 0;
    for (int b = 0; b < SCAN_CHUNKS; ++b) { chunkoff[b] = run; run += partial[b]; }
}

__global__ void k_scanC(const int* __restrict__ deg, const int* __restrict__ chunkoff,
                        int* __restrict__ rowptr) {
    __shared__ int wsum[16];
    int b = blockIdx.x, t = threadIdx.x, lane = t & 63, w = t >> 6;
    int i = b * SCAN_BLOCK + t;
    int v = (i < N_NODES) ? deg[i] : 0;
    for (int off = 1; off < 64; off <<= 1) {
        int u = __shfl_up(v, off, 64);
        if (lane >= off) v += u;
    }
    if (lane == 63) wsum[w] = v;
    __syncthreads();
    if (t == 0) {
        int run = 0;
        for (int k = 0; k < 16; ++k) { int s = wsum[k]; wsum[k] = run; run += s; }
    }
    __syncthreads();
    int incl = v + wsum[w] + chunkoff[b];
    if (i < N_NODES) rowptr[i + 1] = incl;
    if (b == 0 && t == 0) rowptr[0] = 0;
}

// atomic-free CSR fill using precomputed ranks
__global__ void k_scatter(const int* __restrict__ ei, const int* __restrict__ aux,
                          const int* __restrict__ rowptr, int* __restrict__ csr,
                          const int* __restrict__ flags) {
    int t = blockIdx.x * blockDim.x + threadIdx.x;
    int e0 = t * 4;
    if (e0 >= N_EDGES) return;
    int s[4], d[4];
    if (flags[0]) {
        const int4* ps = (const int4*)(ei + 2 * (size_t)e0);
        int4 a = ps[0], b = ps[1];
        s[0] = a.x; s[1] = a.z; s[2] = b.x; s[3] = b.z;
        const int4* pd = (const int4*)(ei + 2 * (size_t)(N_EDGES + e0));
        int4 c = pd[0], g = pd[1];
        d[0] = c.x; d[1] = c.z; d[2] = g.x; d[3] = g.z;
    } else {
        int4 a = *(const int4*)(ei + (size_t)e0);
        s[0] = a.x; s[1] = a.y; s[2] = a.z; s[3] = a.w;
        int4 c = *(const int4*)(ei + (size_t)N_EDGES + e0);
        d[0] = c.x; d[1] = c.y; d[2] = c.z; d[3] = c.w;
    }
    int4 av = *(const int4*)(aux + e0);
    int a4[4] = { av.x, av.y, av.z, av.w };
#pragma unroll
    for (int j = 0; j < 4; ++j) {
        if ((unsigned)s[j] < N_NODES && (unsigned)d[j] < N_NODES)
            csr[rowptr[d[j]] + a4[j]] = s[j];
    }
}

// ---------------- GEMM1 via MFMA ; block = 1 tile (16 nodes), wave = 1 feat-group ----------------
// 25,000 waves (4x round-11). x tile (4KB, contiguous) + W1p (16KB) staged in LDS.
// C/D: col=lane&15, row=quad*4+reg   (verified correct rounds 9-11)
__global__ void __launch_bounds__(256)
k_gemm1(const void* __restrict__ x, const void* __restrict__ W1,
        const unsigned short* __restrict__ W1p,
        unsigned short* __restrict__ h1, const int* __restrict__ flags) {
    __shared__ unsigned short w1s[F_IN * H1F];          // 16 KB
    __shared__ unsigned short xs[16 * XPAD];            // 4.2 KB, padded rows
    int tid  = threadIdx.x;
    int tile = blockIdx.x;                              // 6250 blocks, exact
    int isbf = flags[1];
    if (isbf) {
        // stage W1p: 4 x uint4 per thread, coalesced
        const uint4* src = (const uint4*)W1p;
        uint4*       dst = (uint4*)w1s;
#pragma unroll
        for (int k = 0; k < 4; ++k) dst[tid + k * 256] = src[tid + k * 256];
        // stage x tile: 16 rows x 256B = 4KB contiguous; 8 shorts per thread
        const short* xp = (const short*)x + (size_t)tile * 16 * F_IN;
        int r = tid >> 4, c = tid & 15;
        *(bf16x8*)(xs + r * XPAD + c * 8) = *(const bf16x8*)(xp + tid * 8);
    }
    __syncthreads();

    int wave = tid >> 6, lane = tid & 63;
    int col = lane & 15, quad = lane >> 4;
    int fg = wave;                                      // feature group 0..3

    if (isbf) {
        // A fragments from padded LDS
        bf16x8 afr[4];
#pragma unroll
        for (int kc = 0; kc < 4; ++kc)
            afr[kc] = *(const bf16x8*)(xs + col * XPAD + kc * 32 + quad * 8);
        f32x4 acc;
#pragma unroll
        for (int r = 0; r < 4; ++r) acc[r] = 0.f;
#pragma unroll
        for (int kc = 0; kc < 4; ++kc) {
            bf16x8 bfr = *(const bf16x8*)(w1s + (((kc * 4 + fg) * 64 + lane) * 8));
            acc = __builtin_amdgcn_mfma_f32_16x16x32_bf16(afr[kc], bfr, acc, 0, 0, 0);
        }
#pragma unroll
        for (int r = 0; r < 4; ++r)
            h1[(size_t)(tile * 16 + quad * 4 + r) * H1F + fg * 16 + col] = f2us(acc[r]);
    } else {
        // f32 fallback: shfl-broadcast, 4 nodes per wave
        const float* wfp = (const float*)W1;
        for (int i = 0; i < 4; ++i) {
            int n = tile * 16 + wave * 4 + i;
            const float2* xr = (const float2*)((const float*)x + (size_t)n * F_IN);
            float2 my = xr[lane];
            float acc = 0.f;
#pragma unroll 16
            for (int k = 0; k < 64; ++k) {
                float x0 = __shfl(my.x, k, 64);
                float x1 = __shfl(my.y, k, 64);
                acc += x0 * wfp[(2 * k) * H1F + lane];
                acc += x1 * wfp[(2 * k + 1) * H1F + lane];
            }
            h1[(size_t)n * H1F + lane] = f2us(acc);
        }
    }
}

// ---------------- fused agg1 + bias/ReLU + GEMM2 -> h2(bf16) ; wave per node ----------------
__global__ void k_agg1gemm2(const unsigned short* __restrict__ h1,
                            const float* __restrict__ dinv,
                            const int* __restrict__ rowptr, const int* __restrict__ csr,
                            const void* __restrict__ b1, const void* __restrict__ W2,
                            unsigned short* __restrict__ h2, const int* __restrict__ flags) {
    int n    = (blockIdx.x * blockDim.x + threadIdx.x) >> 6;
    int lane = threadIdx.x & 63;
    if (n >= N_NODES) return;
    int beg = rowptr[n], end = rowptr[n + 1];
    float dn  = dinv[n];
    float acc = dn * us2f(h1[(size_t)n * H1F + lane]);  // self-loop
    int e = beg;
    for (; e + 3 < end; e += 4) {                       // 4-deep MLP
        int s0 = csr[e], s1 = csr[e + 1], s2 = csr[e + 2], s3 = csr[e + 3];
        float w0 = dinv[s0], w1 = dinv[s1], w2 = dinv[s2], w3 = dinv[s3];
        unsigned short v0 = h1[(size_t)s0 * H1F + lane];
        unsigned short v1 = h1[(size_t)s1 * H1F + lane];
        unsigned short v2 = h1[(size_t)s2 * H1F + lane];
        unsigned short v3 = h1[(size_t)s3 * H1F + lane];
        acc += w0 * us2f(v0) + w1 * us2f(v1) + w2 * us2f(v2) + w3 * us2f(v3);
    }
    for (; e < end; ++e) {
        int s = csr[e];
        acc += dinv[s] * us2f(h1[(size_t)s * H1F + lane]);
    }
    acc *= dn;                                          // agg1[n][lane]
    int isbf = flags[1];
    float bv = isbf ? b2f(((const __hip_bfloat16*)b1)[lane]) : ((const float*)b1)[lane];
    float v  = fmaxf(acc + bv, 0.f);                    // relu(agg1 + b1)
    int f = lane & 31, h = lane >> 5;
    float part = 0.f;
    if (isbf) {
        const __hip_bfloat16* w = (const __hip_bfloat16*)W2;
#pragma unroll
        for (int j = 0; j < 32; ++j) {
            int k = h * 32 + j;
            part += __shfl(v, k, 64) * b2f(w[k * H2F + f]);
        }
    } else {
        const float* w = (const float*)W2;
#pragma unroll
        for (int j = 0; j < 32; ++j) {
            int k = h * 32 + j;
            part += __shfl(v, k, 64) * w[k * H2F + f];
        }
    }
    part += __shfl(part, lane ^ 32, 64);                // combine halves
    if (h == 0) h2[(size_t)n * H2F + f] = f2us(part);
}

// ---------------- fused agg2 + final MLP -> out ; half-wave per node ----------------
__global__ void GCN_51737176048479_kernel(const unsigned short* __restrict__ h2,
                                          const float* __restrict__ dinv,
                                          const int* __restrict__ rowptr,
                                          const int* __restrict__ csr,
                                          const void* __restrict__ b2v,
                                          const void* __restrict__ Wf,
                                          const void* __restrict__ bfv,
                                          const void* __restrict__ Wo,
                                          const void* __restrict__ bov,
                                          void* __restrict__ out,
                                          const int* __restrict__ flags) {
    int tid = blockIdx.x * blockDim.x + threadIdx.x;
    int n   = tid >> 5;
    int f   = threadIdx.x & 31;
    if (n >= N_NODES) return;
    int isbf = flags[1];
    int beg = rowptr[n], end = rowptr[n + 1];
    float dn = dinv[n];
    float ar = dn * us2f(h2[(size_t)n * H2F + f]);
    int e = beg;
    for (; e + 3 < end; e += 4) {
        int s0 = csr[e], s1 = csr[e + 1], s2 = csr[e + 2], s3 = csr[e + 3];
        float w0 = dinv[s0], w1 = dinv[s1], w2 = dinv[s2], w3 = dinv[s3];
        unsigned short v0 = h2[(size_t)s0 * H2F + f];
        unsigned short v1 = h2[(size_t)s1 * H2F + f];
        unsigned short v2 = h2[(size_t)s2 * H2F + f];
        unsigned short v3 = h2[(size_t)s3 * H2F + f];
        ar += w0 * us2f(v0) + w1 * us2f(v1) + w2 * us2f(v2) + w3 * us2f(v3);
    }
    for (; e < end; ++e) {
        int s = csr[e];
        ar += dinv[s] * us2f(h2[(size_t)s * H2F + f]);
    }
    ar = ar * dn + ld(b2v, f, isbf);                    // conv2 out (no relu)
    float acc1 = 0.f;
#pragma unroll
    for (int k = 0; k < H2F; ++k)
        acc1 += __shfl(ar, k, 32) * ld(Wf, (size_t)k * H2F + f, isbf);
    float u = fmaxf(acc1 + ld(bfv, f, isbf), 0.f);
    float acc2 = 0.f;
#pragma unroll
    for (int k = 0; k < H2F; ++k)
        acc2 += __shfl(u, k, 32) * ld(Wo, (size_t)k * NCLS + f, isbf);
    float r = acc2 + ld(bov, f, isbf);
    size_t oi = (size_t)n * NCLS + f;
    if (isbf) ((__hip_bfloat16*)out)[oi] = __float2bfloat16(r);
    else      ((float*)out)[oi] = r;
}

extern "C" void kernel_launch(void* const* d_in, const int* in_sizes, int n_in,
                              void* d_out, int out_size, void* d_ws, size_t ws_size,
                              hipStream_t stream) {
    const void* x  = d_in[0];
    const int*  ei = (const int*)d_in[1];
    const void* W1 = d_in[2];
    const void* b1 = d_in[3];
    const void* W2 = d_in[4];
    const void* b2 = d_in[5];
    const void* Wf = d_in[6];
    const void* bf = d_in[7];
    const void* Wo = d_in[8];
    const void* bo = d_in[9];

    // workspace (peak ~48 MB):
    //  deg @0 | rowptr @512K | dinv @1M | flags @1.4M | partial @1.41M | chunkoff @1.42M
    //  W1p @1.5M (16K) | aux @2M (12.8M) | csr @15M (12.8M)
    //  h1 @28M (12.8M bf16) | h2 @41M (6.4M bf16)
    char* ws = (char*)d_ws;
    int*            deg      = (int*)  (ws + 0);
    int*            rowptr   = (int*)  (ws + (512u  << 10));
    float*          dinv     = (float*)(ws + (1024u << 10));
    int*            flags    = (int*)  (ws + (1434u << 10));
    int*            partial  = (int*)  (ws + (1444u << 10));
    int*            chunkoff = (int*)  (ws + (1454u << 10));
    unsigned short* W1p      = (unsigned short*)(ws + (1536u << 10));
    int*            aux      = (int*)  (ws + (2u  << 20));
    int*            csr      = (int*)  (ws + (15u << 20));
    unsigned short* h1       = (unsigned short*)(ws + (28u << 20));
    unsigned short* h2       = (unsigned short*)(ws + (41u << 20));

    const int B = 256;

    k_detect<<<1, 64, 0, stream>>>(x, ei, flags);
    hipMemsetAsync(deg, 0, N_NODES * sizeof(int), stream);
    k_packW1<<<(F_IN * H1F + B - 1) / B, B, 0, stream>>>((const unsigned short*)W1, W1p);
    k_count<<<(N_EDGES / 4 + B - 1) / B, B, 0, stream>>>(ei, deg, aux, flags);
    k_dinv<<<(N_NODES + B - 1) / B, B, 0, stream>>>(deg, dinv);
    k_scanA<<<SCAN_CHUNKS, SCAN_BLOCK, 0, stream>>>(deg, partial);
    k_scanB<<<1, 64, 0, stream>>>(partial, chunkoff);
    k_scanC<<<SCAN_CHUNKS, SCAN_BLOCK, 0, stream>>>(deg, chunkoff, rowptr);
    k_scatter<<<(N_EDGES / 4 + B - 1) / B, B, 0, stream>>>(ei, aux, rowptr, csr, flags);

    k_gemm1<<<NTILES, B, 0, stream>>>(x, W1, W1p, h1, flags);
    k_agg1gemm2<<<(N_NODES * 64 + B - 1) / B, B, 0, stream>>>(h1, dinv, rowptr, csr,
                                                              b1, W2, h2, flags);
    GCN_51737176048479_kernel<<<(N_NODES * 32 + B - 1) / B, B, 0, stream>>>(
        h2, dinv, rowptr, csr, b2, Wf, bf, Wo, bo, d_out, flags);
}

// Round 13
// 599.666 us; speedup vs baseline: 1.1602x; 1.1233x over previous
//
#include <hip/hip_runtime.h>
#include <hip/hip_bf16.h>

#define N_NODES 100000
#define N_EDGES 3200000
#define F_IN    128
#define H1F     64
#define H2F     32
#define NCLS    32
#define SCAN_BLOCK 1024
#define SCAN_CHUNKS ((N_NODES + SCAN_BLOCK - 1) / SCAN_BLOCK)   // 98
#define NTILES (N_NODES / 16)                                   // 6250 exact
#define NCNT   (N_EDGES / 4 / 256)                              // 3125 count blocks
#define XPAD 132                                                // 128+4 shorts: LDS de-alias

typedef __attribute__((ext_vector_type(8))) short bf16x8;
typedef __attribute__((ext_vector_type(4))) float f32x4;

static __device__ __forceinline__ float b2f(__hip_bfloat16 v) {
    return __bfloat162float(v);
}
static __device__ __forceinline__ float us2f(unsigned short u) {
    return __uint_as_float(((unsigned)u) << 16);
}
static __device__ __forceinline__ unsigned short f2us(float f) {
    __hip_bfloat16 h = __float2bfloat16(f);
    return *(unsigned short*)&h;
}
static __device__ __forceinline__ float ld(const void* p, size_t i, int isbf) {
    return isbf ? b2f(((const __hip_bfloat16*)p)[i]) : ((const float*)p)[i];
}

// flags[0] = edge_index is int64 ; flags[1] = float tensors are bf16

__global__ void k_detect(const void* xbuf, const void* eibuf, int* flags) {
    if (threadIdx.x != 0 || blockIdx.x != 0) return;
    const unsigned* ew = (const unsigned*)eibuf;
    int z = 0;
    for (int k = 0; k < 256; ++k) z += (ew[2 * k + 1] == 0u) ? 1 : 0;
    flags[0] = (z >= 200) ? 1 : 0;
    const unsigned* xw = (const unsigned*)xbuf;
    int inr = 0;
    for (int k = 0; k < 256; ++k) {
        unsigned fb = (xw[k] & 0xFFFFu) << 16;
        float a = fabsf(__uint_as_float(fb));
        inr += (a >= 1e-4f && a <= 20.0f) ? 1 : 0;
    }
    flags[1] = (inr >= 160) ? 1 : 0;
}

// ---------- pack W1 into MFMA B-fragment order ----------
__global__ void k_packW1(const unsigned short* __restrict__ W1,
                         unsigned short* __restrict__ W1p) {
    int t = blockIdx.x * blockDim.x + threadIdx.x;      // 8192 threads
    if (t >= F_IN * H1F) return;
    int j    = t & 7;
    int lane = (t >> 3) & 63;
    int fg   = (t >> 9) & 3;
    int kc   = t >> 11;
    int quad = lane >> 4, col = lane & 15;
    W1p[t] = W1[(kc * 32 + quad * 8 + j) * H1F + fg * 16 + col];
}

__global__ void k_dinv(const int* __restrict__ deg, float* __restrict__ dinv) {
    int i = blockIdx.x * blockDim.x + threadIdx.x;
    if (i < N_NODES) dinv[i] = rsqrtf((float)deg[i] + 1.0f);  // +1 self-loop
}

// ---------- 3-phase exclusive scan of deg -> rowptr ----------
__global__ void k_scanA(const int* __restrict__ deg, int* __restrict__ partial) {
    __shared__ int red[16];
    int b = blockIdx.x, t = threadIdx.x;
    int i = b * SCAN_BLOCK + t;
    int v = (i < N_NODES) ? deg[i] : 0;
    for (int off = 32; off; off >>= 1) v += __shfl_down(v, off, 64);
    if ((t & 63) == 0) red[t >> 6] = v;
    __syncthreads();
    if (t == 0) {
        int s = 0;
        for (int k = 0; k < 16; ++k) s += red[k];
        partial[b] = s;
    }
}

__global__ void k_scanB(const int* __restrict__ partial, int* __restrict__ chunkoff) {
    if (threadIdx.x != 0 || blockIdx.x != 0) return;
    int run = 0;
    for (int b = 0; b < SCAN_CHUNKS; ++b) { chunkoff[b] = run; run += partial[b]; }
}

__global__ void k_scanC(const int* __restrict__ deg, const int* __restrict__ chunkoff,
                        int* __restrict__ rowptr) {
    __shared__ int wsum[16];
    int b = blockIdx.x, t = threadIdx.x, lane = t & 63, w = t >> 6;
    int i = b * SCAN_BLOCK + t;
    int v = (i < N_NODES) ? deg[i] : 0;
    for (int off = 1; off < 64; off <<= 1) {
        int u = __shfl_up(v, off, 64);
        if (lane >= off) v += u;
    }
    if (lane == 63) wsum[w] = v;
    __syncthreads();
    if (t == 0) {
        int run = 0;
        for (int k = 0; k < 16; ++k) { int s = wsum[k]; wsum[k] = run; run += s; }
    }
    __syncthreads();
    int incl = v + wsum[w] + chunkoff[b];
    if (i < N_NODES) rowptr[i + 1] = incl;
    if (b == 0 && t == 0) rowptr[0] = 0;
}

// atomic-free CSR fill using precomputed ranks
__global__ void k_scatter(const int* __restrict__ ei, const int* __restrict__ aux,
                          const int* __restrict__ rowptr, int* __restrict__ csr,
                          const int* __restrict__ flags) {
    int t = blockIdx.x * blockDim.x + threadIdx.x;
    int e0 = t * 4;
    if (e0 >= N_EDGES) return;
    int s[4], d[4];
    if (flags[0]) {
        const int4* ps = (const int4*)(ei + 2 * (size_t)e0);
        int4 a = ps[0], b = ps[1];
        s[0] = a.x; s[1] = a.z; s[2] = b.x; s[3] = b.z;
        const int4* pd = (const int4*)(ei + 2 * (size_t)(N_EDGES + e0));
        int4 c = pd[0], g = pd[1];
        d[0] = c.x; d[1] = c.z; d[2] = g.x; d[3] = g.z;
    } else {
        int4 a = *(const int4*)(ei + (size_t)e0);
        s[0] = a.x; s[1] = a.y; s[2] = a.z; s[3] = a.w;
        int4 c = *(const int4*)(ei + (size_t)N_EDGES + e0);
        d[0] = c.x; d[1] = c.y; d[2] = c.z; d[3] = c.w;
    }
    int4 av = *(const int4*)(aux + e0);
    int a4[4] = { av.x, av.y, av.z, av.w };
#pragma unroll
    for (int j = 0; j < 4; ++j) {
        if ((unsigned)s[j] < N_NODES && (unsigned)d[j] < N_NODES)
            csr[rowptr[d[j]] + a4[j]] = s[j];
    }
}

// ---------------- FUSED front-end: gemm1 (MFMA) blocks interleaved with count blocks ----
// blk%3==0 -> histogram+rank block (3125 of them, covers all edges)
// else     -> gemm1 tile block     (6250 of them, covers all tiles)
// Interleave keeps both types co-resident per CU: MFMA/LDS work overlaps atomic latency.
__global__ void __launch_bounds__(256)
k_front(const void* __restrict__ x, const void* __restrict__ W1,
        const unsigned short* __restrict__ W1p, const int* __restrict__ ei,
        int* __restrict__ deg, int* __restrict__ aux,
        unsigned short* __restrict__ h1, const int* __restrict__ flags) {
    __shared__ unsigned short w1s[F_IN * H1F];          // 16 KB
    __shared__ unsigned short xs[16 * XPAD];            // 4.2 KB
    int blk = blockIdx.x, tid = threadIdx.x;

    if (blk % 3 == 0) {
        // -------- histogram + per-edge rank (k_count body) --------
        int t = (blk / 3) * 256 + tid;
        int e0 = t * 4;
        if (e0 >= N_EDGES) return;
        int d[4];
        if (flags[0]) {
            const int4* p = (const int4*)(ei + 2 * (size_t)(N_EDGES + e0));
            int4 a = p[0], b = p[1];
            d[0] = a.x; d[1] = a.z; d[2] = b.x; d[3] = b.z;
        } else {
            int4 a = *(const int4*)(ei + (size_t)N_EDGES + e0);
            d[0] = a.x; d[1] = a.y; d[2] = a.z; d[3] = a.w;
        }
        int p0 = ((unsigned)d[0] < N_NODES) ? atomicAdd(&deg[d[0]], 1) : 0;
        int p1 = ((unsigned)d[1] < N_NODES) ? atomicAdd(&deg[d[1]], 1) : 0;
        int p2 = ((unsigned)d[2] < N_NODES) ? atomicAdd(&deg[d[2]], 1) : 0;
        int p3 = ((unsigned)d[3] < N_NODES) ? atomicAdd(&deg[d[3]], 1) : 0;
        *(int4*)(aux + e0) = make_int4(p0, p1, p2, p3);
        return;
    }

    // -------- gemm1 tile (round-12 body) --------
    int tile = blk - blk / 3 - 1;                       // 0..6249, exact bijection
    int isbf = flags[1];
    if (isbf) {
        const uint4* src = (const uint4*)W1p;
        uint4*       dst = (uint4*)w1s;
#pragma unroll
        for (int k = 0; k < 4; ++k) dst[tid + k * 256] = src[tid + k * 256];
        const short* xp = (const short*)x + (size_t)tile * 16 * F_IN;
        int r = tid >> 4, c = tid & 15;
        *(bf16x8*)(xs + r * XPAD + c * 8) = *(const bf16x8*)(xp + tid * 8);
    }
    __syncthreads();

    int wave = tid >> 6, lane = tid & 63;
    int col = lane & 15, quad = lane >> 4;
    int fg = wave;

    if (isbf) {
        bf16x8 afr[4];
#pragma unroll
        for (int kc = 0; kc < 4; ++kc)
            afr[kc] = *(const bf16x8*)(xs + col * XPAD + kc * 32 + quad * 8);
        f32x4 acc;
#pragma unroll
        for (int r = 0; r < 4; ++r) acc[r] = 0.f;
#pragma unroll
        for (int kc = 0; kc < 4; ++kc) {
            bf16x8 bfr = *(const bf16x8*)(w1s + (((kc * 4 + fg) * 64 + lane) * 8));
            acc = __builtin_amdgcn_mfma_f32_16x16x32_bf16(afr[kc], bfr, acc, 0, 0, 0);
        }
#pragma unroll
        for (int r = 0; r < 4; ++r)
            h1[(size_t)(tile * 16 + quad * 4 + r) * H1F + fg * 16 + col] = f2us(acc[r]);
    } else {
        const float* wfp = (const float*)W1;
        for (int i = 0; i < 4; ++i) {
            int n = tile * 16 + wave * 4 + i;
            const float2* xr = (const float2*)((const float*)x + (size_t)n * F_IN);
            float2 my = xr[lane];
            float acc = 0.f;
#pragma unroll 16
            for (int k = 0; k < 64; ++k) {
                float x0 = __shfl(my.x, k, 64);
                float x1 = __shfl(my.y, k, 64);
                acc += x0 * wfp[(2 * k) * H1F + lane];
                acc += x1 * wfp[(2 * k + 1) * H1F + lane];
            }
            h1[(size_t)n * H1F + lane] = f2us(acc);
        }
    }
}

// ---------------- fused agg1 + bias/ReLU + GEMM2 -> h2(bf16) ; wave per node ----------------
__global__ void k_agg1gemm2(const unsigned short* __restrict__ h1,
                            const float* __restrict__ dinv,
                            const int* __restrict__ rowptr, const int* __restrict__ csr,
                            const void* __restrict__ b1, const void* __restrict__ W2,
                            unsigned short* __restrict__ h2, const int* __restrict__ flags) {
    int n    = (blockIdx.x * blockDim.x + threadIdx.x) >> 6;
    int lane = threadIdx.x & 63;
    if (n >= N_NODES) return;
    int beg = rowptr[n], end = rowptr[n + 1];
    float dn  = dinv[n];
    float acc = dn * us2f(h1[(size_t)n * H1F + lane]);  // self-loop
    int e = beg;
    for (; e + 3 < end; e += 4) {                       // 4-deep MLP
        int s0 = csr[e], s1 = csr[e + 1], s2 = csr[e + 2], s3 = csr[e + 3];
        float w0 = dinv[s0], w1 = dinv[s1], w2 = dinv[s2], w3 = dinv[s3];
        unsigned short v0 = h1[(size_t)s0 * H1F + lane];
        unsigned short v1 = h1[(size_t)s1 * H1F + lane];
        unsigned short v2 = h1[(size_t)s2 * H1F + lane];
        unsigned short v3 = h1[(size_t)s3 * H1F + lane];
        acc += w0 * us2f(v0) + w1 * us2f(v1) + w2 * us2f(v2) + w3 * us2f(v3);
    }
    for (; e < end; ++e) {
        int s = csr[e];
        acc += dinv[s] * us2f(h1[(size_t)s * H1F + lane]);
    }
    acc *= dn;                                          // agg1[n][lane]
    int isbf = flags[1];
    float bv = isbf ? b2f(((const __hip_bfloat16*)b1)[lane]) : ((const float*)b1)[lane];
    float v  = fmaxf(acc + bv, 0.f);                    // relu(agg1 + b1)
    int f = lane & 31, h = lane >> 5;
    float part = 0.f;
    if (isbf) {
        const __hip_bfloat16* w = (const __hip_bfloat16*)W2;
#pragma unroll
        for (int j = 0; j < 32; ++j) {
            int k = h * 32 + j;
            part += __shfl(v, k, 64) * b2f(w[k * H2F + f]);
        }
    } else {
        const float* w = (const float*)W2;
#pragma unroll
        for (int j = 0; j < 32; ++j) {
            int k = h * 32 + j;
            part += __shfl(v, k, 64) * w[k * H2F + f];
        }
    }
    part += __shfl(part, lane ^ 32, 64);                // combine halves
    if (h == 0) h2[(size_t)n * H2F + f] = f2us(part);
}

// ---------------- fused agg2 + final MLP -> out ; half-wave per node ----------------
__global__ void GCN_51737176048479_kernel(const unsigned short* __restrict__ h2,
                                          const float* __restrict__ dinv,
                                          const int* __restrict__ rowptr,
                                          const int* __restrict__ csr,
                                          const void* __restrict__ b2v,
                                          const void* __restrict__ Wf,
                                          const void* __restrict__ bfv,
                                          const void* __restrict__ Wo,
                                          const void* __restrict__ bov,
                                          void* __restrict__ out,
                                          const int* __restrict__ flags) {
    int tid = blockIdx.x * blockDim.x + threadIdx.x;
    int n   = tid >> 5;
    int f   = threadIdx.x & 31;
    if (n >= N_NODES) return;
    int isbf = flags[1];
    int beg = rowptr[n], end = rowptr[n + 1];
    float dn = dinv[n];
    float ar = dn * us2f(h2[(size_t)n * H2F + f]);
    int e = beg;
    for (; e + 3 < end; e += 4) {
        int s0 = csr[e], s1 = csr[e + 1], s2 = csr[e + 2], s3 = csr[e + 3];
        float w0 = dinv[s0], w1 = dinv[s1], w2 = dinv[s2], w3 = dinv[s3];
        unsigned short v0 = h2[(size_t)s0 * H2F + f];
        unsigned short v1 = h2[(size_t)s1 * H2F + f];
        unsigned short v2 = h2[(size_t)s2 * H2F + f];
        unsigned short v3 = h2[(size_t)s3 * H2F + f];
        ar += w0 * us2f(v0) + w1 * us2f(v1) + w2 * us2f(v2) + w3 * us2f(v3);
    }
    for (; e < end; ++e) {
        int s = csr[e];
        ar += dinv[s] * us2f(h2[(size_t)s * H2F + f]);
    }
    ar = ar * dn + ld(b2v, f, isbf);                    // conv2 out (no relu)
    float acc1 = 0.f;
#pragma unroll
    for (int k = 0; k < H2F; ++k)
        acc1 += __shfl(ar, k, 32) * ld(Wf, (size_t)k * H2F + f, isbf);
    float u = fmaxf(acc1 + ld(bfv, f, isbf), 0.f);
    float acc2 = 0.f;
#pragma unroll
    for (int k = 0; k < H2F; ++k)
        acc2 += __shfl(u, k, 32) * ld(Wo, (size_t)k * NCLS + f, isbf);
    float r = acc2 + ld(bov, f, isbf);
    size_t oi = (size_t)n * NCLS + f;
    if (isbf) ((__hip_bfloat16*)out)[oi] = __float2bfloat16(r);
    else      ((float*)out)[oi] = r;
}

extern "C" void kernel_launch(void* const* d_in, const int* in_sizes, int n_in,
                              void* d_out, int out_size, void* d_ws, size_t ws_size,
                              hipStream_t stream) {
    const void* x  = d_in[0];
    const int*  ei = (const int*)d_in[1];
    const void* W1 = d_in[2];
    const void* b1 = d_in[3];
    const void* W2 = d_in[4];
    const void* b2 = d_in[5];
    const void* Wf = d_in[6];
    const void* bf = d_in[7];
    const void* Wo = d_in[8];
    const void* bo = d_in[9];

    // workspace (peak ~48 MB):
    //  deg @0 | rowptr @512K | dinv @1M | flags @1.4M | partial @1.41M | chunkoff @1.42M
    //  W1p @1.5M (16K) | aux @2M (12.8M) | csr @15M (12.8M)
    //  h1 @28M (12.8M bf16) | h2 @41M (6.4M bf16)
    char* ws = (char*)d_ws;
    int*            deg      = (int*)  (ws + 0);
    int*            rowptr   = (int*)  (ws + (512u  << 10));
    float*          dinv     = (float*)(ws + (1024u << 10));
    int*            flags    = (int*)  (ws + (1434u << 10));
    int*            partial  = (int*)  (ws + (1444u << 10));
    int*            chunkoff = (int*)  (ws + (1454u << 10));
    unsigned short* W1p      = (unsigned short*)(ws + (1536u << 10));
    int*            aux      = (int*)  (ws + (2u  << 20));
    int*            csr      = (int*)  (ws + (15u << 20));
    unsigned short* h1       = (unsigned short*)(ws + (28u << 20));
    unsigned short* h2       = (unsigned short*)(ws + (41u << 20));

    const int B = 256;

    k_detect<<<1, 64, 0, stream>>>(x, ei, flags);
    hipMemsetAsync(deg, 0, N_NODES * sizeof(int), stream);
    k_packW1<<<(F_IN * H1F + B - 1) / B, B, 0, stream>>>((const unsigned short*)W1, W1p);

    // fused gemm1 + histogram (independent work, interleaved for co-residency)
    k_front<<<NTILES + NCNT, B, 0, stream>>>(x, W1, W1p, ei, deg, aux, h1, flags);

    k_dinv<<<(N_NODES + B - 1) / B, B, 0, stream>>>(deg, dinv);
    k_scanA<<<SCAN_CHUNKS, SCAN_BLOCK, 0, stream>>>(deg, partial);
    k_scanB<<<1, 64, 0, stream>>>(partial, chunkoff);
    k_scanC<<<SCAN_CHUNKS, SCAN_BLOCK, 0, stream>>>(deg, chunkoff, rowptr);
    k_scatter<<<(N_EDGES / 4 + B - 1) / B, B, 0, stream>>>(ei, aux, rowptr, csr, flags);

    k_agg1gemm2<<<(N_NODES * 64 + B - 1) / B, B, 0, stream>>>(h1, dinv, rowptr, csr,
                                                              b1, W2, h2, flags);
    GCN_51737176048479_kernel<<<(N_NODES * 32 + B - 1) / B, B, 0, stream>>>(
        h2, dinv, rowptr, csr, b2, Wf, bf, Wo, bo, d_out, flags);
}